// Round 11
// baseline (786.221 us; speedup 1.0000x reference)
//
#include <hip/hip_runtime.h>
#include <hip/hip_bf16.h>
#include <math.h>

#define N_NODES 50000
#define N_EDGES 800000
#define D_IN    128
#define H1_     256
#define H2_     128
#define NG      64
#define NC_     2
#define BN_EPS  1e-5f
#define PAD_    64      // ELL slots per node; deg~Poisson(16), P(deg>64)~2e-18
#define NBLK_G  782     // gemm grid blocks = ceil(50000/64)

typedef __attribute__((ext_vector_type(8))) short bf16x8;
typedef __attribute__((ext_vector_type(4))) float f32x4;

__device__ __forceinline__ float bf2f(unsigned short u) {
    unsigned int v = ((unsigned int)u) << 16;
    return __uint_as_float(v);
}
__device__ __forceinline__ unsigned short f2bf(float f) {
    __hip_bfloat16 h = __float2bfloat16(f);
    return *reinterpret_cast<unsigned short*>(&h);
}

// ---------------------------------------------------------------------------
// padded-ELL adjacency build (no prefix scan needed)
// ---------------------------------------------------------------------------
__global__ void degree_kernel(const int* __restrict__ ei, int* __restrict__ deg)
{
    int e = blockIdx.x * 256 + threadIdx.x;
    if (e < N_EDGES) atomicAdd(&deg[ei[N_EDGES + e]], 1);
}

__global__ void fill_kernel(const int* __restrict__ ei, int* __restrict__ cursor,
                            int* __restrict__ ell)
{
    int e = blockIdx.x * 256 + threadIdx.x;
    if (e < N_EDGES) {
        int d = ei[N_EDGES + e];
        int off = atomicAdd(&cursor[d], 1);
        if (off < PAD_) ell[d * PAD_ + off] = ei[e];   // clamp: memory safety
    }
}

// ---------------------------------------------------------------------------
// f32 -> bf16 convert (4 elems/thread)
// ---------------------------------------------------------------------------
__global__ void conv_bf16_kernel(const float* __restrict__ in,
                                 unsigned short* __restrict__ out, int n4)
{
    int i = blockIdx.x * 256 + threadIdx.x;
    if (i < n4) {
        float4 v = ((const float4*)in)[i];
        ushort4 o;
        o.x = f2bf(v.x); o.y = f2bf(v.y); o.z = f2bf(v.z); o.w = f2bf(v.w);
        ((ushort4*)out)[i] = o;
    }
}

// ---------------------------------------------------------------------------
// weight swizzle into per-nt-contiguous MFMA fragment slices, f32 -> bf16.
// slice nt = [NKT_T frags of [Wl;Wr] | NKT_R frags of Wp]
// fragment element j = W[kt*32 + (lane>>4)*8 + j][nt*16 + (lane&15)]
// ---------------------------------------------------------------------------
template<int K1, int K2, int HOUT>
__global__ void wswz_kernel(const float* __restrict__ Wl, const float* __restrict__ Wr,
                            const float* __restrict__ Wp,
                            unsigned short* __restrict__ wcomb)
{
    constexpr int NKT_T = (K1 + K2) / 32;
    constexpr int NKT_R = K2 / 32;
    constexpr int F = NKT_T + NKT_R;
    constexpr int NNT = HOUT / 16;
    int idx = blockIdx.x * 256 + threadIdx.x;   // fragment-lane id
    if (idx >= NNT * F * 64) return;
    int lane = idx & 63, fi = idx >> 6;
    int f = fi % F, nt = fi / F;
    int col = nt * 16 + (lane & 15);
    int kq8 = (lane >> 4) * 8;
    unsigned short o[8];
    if (f < NKT_T) {
        int k0 = f * 32 + kq8;
        #pragma unroll
        for (int j = 0; j < 8; ++j) {
            int k = k0 + j;
            float v = (k < K1) ? Wl[(size_t)k * HOUT + col]
                               : Wr[(size_t)(k - K1) * HOUT + col];
            o[j] = f2bf(v);
        }
    } else {
        int k0 = (f - NKT_T) * 32 + kq8;
        #pragma unroll
        for (int j = 0; j < 8; ++j)
            o[j] = f2bf(Wp[(size_t)(k0 + j) * HOUT + col]);
    }
    ushort4 lo, hi;
    lo.x = o[0]; lo.y = o[1]; lo.z = o[2]; lo.w = o[3];
    hi.x = o[4]; hi.y = o[5]; hi.z = o[6]; hi.w = o[7];
    ((ushort4*)wcomb)[idx * 2]     = lo;
    ((ushort4*)wcomb)[idx * 2 + 1] = hi;
}

// ---------------------------------------------------------------------------
// gather-mean from bf16 features over padded-ELL adjacency
// ---------------------------------------------------------------------------
template<int D>
__global__ __launch_bounds__(256) void gather_mean_bf16_kernel(
    const unsigned short* __restrict__ xb, const int* __restrict__ deg,
    const int* __restrict__ ell, unsigned short* __restrict__ mean)
{
    constexpr int GT = D / 4;         // lanes per node, 4 bf16 (8B) per lane
    constexpr int NGRP = 256 / GT;
    int grp = threadIdx.x / GT;
    int t   = threadIdx.x % GT;
    int n = blockIdx.x * NGRP + grp;
    if (n >= N_NODES) return;
    int dn = deg[n];
    int cnt = min(dn, PAD_);
    const int* lst = ell + n * PAD_;
    const ushort4* xv = (const ushort4*)xb;
    float a0 = 0.f, a1 = 0.f, a2 = 0.f, a3 = 0.f;
    int e = 0;
    for (; e + 1 < cnt; e += 2) {
        int s0 = lst[e], s1 = lst[e + 1];
        ushort4 v0 = xv[(size_t)s0 * GT + t];
        ushort4 v1 = xv[(size_t)s1 * GT + t];
        a0 += bf2f(v0.x) + bf2f(v1.x);
        a1 += bf2f(v0.y) + bf2f(v1.y);
        a2 += bf2f(v0.z) + bf2f(v1.z);
        a3 += bf2f(v0.w) + bf2f(v1.w);
    }
    if (e < cnt) {
        int s0 = lst[e];
        ushort4 v0 = xv[(size_t)s0 * GT + t];
        a0 += bf2f(v0.x); a1 += bf2f(v0.y); a2 += bf2f(v0.z); a3 += bf2f(v0.w);
    }
    float inv = 1.0f / fmaxf((float)dn, 1.0f);
    ushort4 o;
    o.x = f2bf(a0 * inv); o.y = f2bf(a1 * inv);
    o.z = f2bf(a2 * inv); o.w = f2bf(a3 * inv);
    ((ushort4*)mean)[(size_t)n * GT + t] = o;
}

// ---------------------------------------------------------------------------
// MFMA GEMM (direct global weight reads — r8 structure) + fused epilogue.
// BN column stats: per-block PARTIAL SUMS (plain stores, contention-free);
// the 782-way reduction happens in bn_finalize. No global atomics here.
// C/D: col=lane&15, row=(lane>>4)*4+reg  [m89]
// ---------------------------------------------------------------------------
template<int K1, int K2, int HOUT, bool R_BF16>
__global__ __launch_bounds__(256) void gemm_mfma_kernel(
    const unsigned short* __restrict__ meanb,   // [N][K1] bf16
    const unsigned short* __restrict__ selfb,   // [N][K2] bf16
    const unsigned short* __restrict__ wcomb,   // per-nt weight slices
    const float* __restrict__ bl, const float* __restrict__ bp,
    float* __restrict__ tout,
    void* __restrict__ rout,
    float* __restrict__ psS, float* __restrict__ psQ)
{
    constexpr int NKT_T = (K1 + K2) / 32;
    constexpr int NKT_R = K2 / 32;
    constexpr int NKT_M = K1 / 32;
    constexpr int F     = NKT_T + NKT_R;
    constexpr int NNT   = HOUT / 16;
    __shared__ float sred_s[4][HOUT];
    __shared__ float sred_q[4][HOUT];

    int tid = threadIdx.x;
    int w = tid >> 6, lane = tid & 63;
    int lm = lane & 15, kq = lane >> 4;
    int arow = blockIdx.x * 64 + w * 16 + lm;
    int lrow = (arow < N_NODES) ? arow : (N_NODES - 1);

    // ---- A fragments (registers) ----
    bf16x8 af[NKT_T];
    {
        const unsigned short* mrow = meanb + (size_t)lrow * K1 + kq * 8;
        const unsigned short* srow = selfb + (size_t)lrow * K2 + kq * 8;
        #pragma unroll
        for (int kt = 0; kt < NKT_M; ++kt)
            af[kt] = *(const bf16x8*)(mrow + kt * 32);
        #pragma unroll
        for (int kt = 0; kt < NKT_R; ++kt)
            af[NKT_M + kt] = *(const bf16x8*)(srow + kt * 32);
    }

    int orow0 = blockIdx.x * 64 + w * 16 + kq * 4;
    f32x4 tv[NNT];
    float ssq[4] = {0.f, 0.f, 0.f, 0.f};

    #pragma unroll
    for (int nt = 0; nt < NNT; ++nt) {
        // t = [mean|x] @ [Wl;Wr]
        f32x4 acc = {0.f, 0.f, 0.f, 0.f};
        #pragma unroll
        for (int kt = 0; kt < NKT_T; ++kt) {
            bf16x8 bw = *(const bf16x8*)(wcomb + ((size_t)(nt * F + kt) * 64 + lane) * 8);
            acc = __builtin_amdgcn_mfma_f32_16x16x32_bf16(af[kt], bw, acc, 0, 0, 0);
        }
        float blj = bl[nt * 16 + lm];
        #pragma unroll
        for (int r = 0; r < 4; ++r) {
            acc[r] += blj;
            ssq[r] += acc[r] * acc[r];
        }
        tv[nt] = acc;

        // r = x @ Wp  (store immediately, fire-and-forget)
        f32x4 racc = {0.f, 0.f, 0.f, 0.f};
        #pragma unroll
        for (int kt = 0; kt < NKT_R; ++kt) {
            bf16x8 bw = *(const bf16x8*)(wcomb + ((size_t)(nt * F + NKT_T + kt) * 64 + lane) * 8);
            racc = __builtin_amdgcn_mfma_f32_16x16x32_bf16(af[NKT_M + kt], bw, racc, 0, 0, 0);
        }
        float bpj = bp[nt * 16 + lm];
        #pragma unroll
        for (int r = 0; r < 4; ++r) {
            int orow = orow0 + r;
            if (orow < N_NODES) {
                float v = racc[r] + bpj;
                if (R_BF16)
                    ((unsigned short*)rout)[(size_t)orow * HOUT + nt * 16 + lm] = f2bf(v);
                else
                    ((float*)rout)[(size_t)orow * HOUT + nt * 16 + lm] = v;
            }
        }
    }

    // ---- row L2-norm: reduce ssq over the 16 col-lanes ----
    #pragma unroll
    for (int off = 1; off <= 8; off <<= 1)
        #pragma unroll
        for (int r = 0; r < 4; ++r)
            ssq[r] += __shfl_xor(ssq[r], off);
    float inv[4];
    #pragma unroll
    for (int r = 0; r < 4; ++r)
        inv[r] = 1.0f / fmaxf(sqrtf(ssq[r]), 1e-12f);

    // ---- normalize, store t, accumulate BN column stats ----
    #pragma unroll
    for (int nt = 0; nt < NNT; ++nt) {
        float cs = 0.f, cq = 0.f;
        #pragma unroll
        for (int r = 0; r < 4; ++r) {
            int orow = orow0 + r;
            float v = tv[nt][r] * inv[r];
            if (orow < N_NODES) {
                tout[(size_t)orow * HOUT + nt * 16 + lm] = v;
                cs += v; cq += v * v;
            }
        }
        cs += __shfl_xor(cs, 16); cs += __shfl_xor(cs, 32);
        cq += __shfl_xor(cq, 16); cq += __shfl_xor(cq, 32);
        if (kq == 0) {
            sred_s[w][nt * 16 + lm] = cs;
            sred_q[w][nt * 16 + lm] = cq;
        }
    }
    __syncthreads();
    if (tid < HOUT) {
        float s = sred_s[0][tid] + sred_s[1][tid] + sred_s[2][tid] + sred_s[3][tid];
        float q = sred_q[0][tid] + sred_q[1][tid] + sred_q[2][tid] + sred_q[3][tid];
        psS[(size_t)blockIdx.x * HOUT + tid] = s;   // plain store, no atomic
        psQ[(size_t)blockIdx.x * HOUT + tid] = q;
    }
}

// ---------------------------------------------------------------------------
// reduce per-block partial sums -> BN scale/shift (coalesced over blocks)
// ---------------------------------------------------------------------------
template<int H>
__global__ void bn_finalize(const float* __restrict__ psS, const float* __restrict__ psQ,
                            const float* __restrict__ g, const float* __restrict__ be,
                            float* __restrict__ scale, float* __restrict__ shift)
{
    int j = threadIdx.x;
    if (j < H) {
        float s = 0.f, q = 0.f;
        #pragma unroll 4
        for (int b = 0; b < NBLK_G; ++b) {
            s += psS[(size_t)b * H + j];
            q += psQ[(size_t)b * H + j];
        }
        float mu = s / (float)N_NODES;
        float var = q / (float)N_NODES - mu * mu;
        float sc = g[j] * rsqrtf(var + BN_EPS);
        scale[j] = sc;
        shift[j] = be[j] - mu * sc;
    }
}

// ---------------------------------------------------------------------------
// layer 0 epilogue: h0b = bf16( relu(t*scale+shift) + r0b )
// ---------------------------------------------------------------------------
__global__ void ew0_kernel(const float4* __restrict__ t, const ushort4* __restrict__ rb,
                           const float* __restrict__ scale, const float* __restrict__ shift,
                           ushort4* __restrict__ h0b)
{
    int gid = blockIdx.x * 256 + threadIdx.x;
    if (gid >= N_NODES * H1_ / 4) return;
    int j4 = gid & (H1_ / 4 - 1);
    float4 sc = *(const float4*)(scale + j4 * 4);
    float4 sh = *(const float4*)(shift + j4 * 4);
    float4 tv = t[gid];
    ushort4 rv = rb[gid];
    ushort4 hb;
    hb.x = f2bf(fmaxf(tv.x * sc.x + sh.x, 0.f) + bf2f(rv.x));
    hb.y = f2bf(fmaxf(tv.y * sc.y + sh.y, 0.f) + bf2f(rv.y));
    hb.z = f2bf(fmaxf(tv.z * sc.z + sh.z, 0.f) + bf2f(rv.z));
    hb.w = f2bf(fmaxf(tv.w * sc.w + sh.w, 0.f) + bf2f(rv.w));
    h0b[gid] = hb;
}

// ---------------------------------------------------------------------------
// layer 1 epilogue fused with mean-pool scatter (batch sorted -> run-length)
// ---------------------------------------------------------------------------
__global__ __launch_bounds__(H2_) void ew1_pool_kernel(
    const float* __restrict__ t, const float* __restrict__ r,
    const float* __restrict__ scale, const float* __restrict__ shift,
    const int* __restrict__ batch,
    float* __restrict__ pooled, float* __restrict__ pcnt)
{
    int j = threadIdx.x;
    int n0 = blockIdx.x * 64;
    int nend = min(n0 + 64, N_NODES);
    float acc = 0.f, cacc = 0.f;
    int run = -1;
    float sc = scale[j], sh = shift[j];
    for (int n = n0; n < nend; ++n) {
        int b = batch[n];
        if (b != run) {
            if (run >= 0) {
                atomicAdd(&pooled[run * H2_ + j], acc);
                if (j == 0) atomicAdd(&pcnt[run], cacc);
            }
            run = b; acc = 0.f; cacc = 0.f;
        }
        float v = t[(size_t)n * H2_ + j] * sc + sh;
        v = fmaxf(v, 0.f) + r[(size_t)n * H2_ + j];
        acc += v;
        cacc += 1.f;
    }
    if (run >= 0) {
        atomicAdd(&pooled[run * H2_ + j], acc);
        if (j == 0) atomicAdd(&pcnt[run], cacc);
    }
}

// ---------------------------------------------------------------------------
__global__ void pool_fin_kernel(const float* __restrict__ pooled, const float* __restrict__ pcnt,
                                float* __restrict__ emb, float* __restrict__ emb_out)
{
    int gid = blockIdx.x * blockDim.x + threadIdx.x;
    if (gid < NG * H2_) {
        int g = gid >> 7;
        float v = pooled[gid] / fmaxf(pcnt[g], 1.0f);
        emb[gid] = v;
        emb_out[gid] = v;
    }
}

// ---------------------------------------------------------------------------
// classifier MLP, single block, 1024 threads (16 waves for latency hiding)
// ---------------------------------------------------------------------------
__global__ __launch_bounds__(1024) void classifier_kernel(
    const float* __restrict__ emb,
    const float* __restrict__ Wc0, const float* __restrict__ bc0,
    const float* __restrict__ gc0, const float* __restrict__ bec0,
    const float* __restrict__ Wc1, const float* __restrict__ bc1,
    const float* __restrict__ gc1, const float* __restrict__ bec1,
    const float* __restrict__ Wc2, const float* __restrict__ bc2,
    float* __restrict__ logits)
{
    __shared__ float es[NG][H2_];     // 32 KB: emb, later z1
    __shared__ float z0s[NG][256];    // 64 KB
    __shared__ float red_s[1024];     // 4 KB
    __shared__ float red_q[1024];     // 4 KB
    __shared__ float scs[256], shs[256];
    int tid = threadIdx.x;
    for (int i = tid; i < NG * H2_; i += 1024) es[i >> 7][i & 127] = emb[i];
    __syncthreads();

    { // stage A: z0 = relu(bn(emb @ Wc0 + bc0))  [64x128 @ 128x256]
        int j = tid & 255, rg = tid >> 8;          // 4 groups x 16 rows
        float acc[16];
        float b = bc0[j];
        #pragma unroll
        for (int r = 0; r < 16; ++r) acc[r] = b;
        #pragma unroll 4
        for (int k = 0; k < H2_; ++k) {
            float w = Wc0[k * 256 + j];
            #pragma unroll
            for (int r = 0; r < 16; ++r) acc[r] += es[rg * 16 + r][k] * w;
        }
        float cs = 0.f, cq = 0.f;
        #pragma unroll
        for (int r = 0; r < 16; ++r) { cs += acc[r]; cq += acc[r] * acc[r]; }
        red_s[rg * 256 + j] = cs;
        red_q[rg * 256 + j] = cq;
        __syncthreads();
        if (tid < 256) {
            float s = red_s[tid] + red_s[256 + tid] + red_s[512 + tid] + red_s[768 + tid];
            float q = red_q[tid] + red_q[256 + tid] + red_q[512 + tid] + red_q[768 + tid];
            float mu = s * (1.0f / NG);
            float var = q * (1.0f / NG) - mu * mu;
            float sc = gc0[tid] * rsqrtf(var + BN_EPS);
            scs[tid] = sc;
            shs[tid] = bec0[tid] - mu * sc;
        }
        __syncthreads();
        float sc = scs[j], sh = shs[j];
        #pragma unroll
        for (int r = 0; r < 16; ++r)
            z0s[rg * 16 + r][j] = fmaxf(acc[r] * sc + sh, 0.f);
    }
    __syncthreads();

    { // stage B: z1 = relu(bn(z0 @ Wc1 + bc1))  [64x256 @ 256x128] -> es
        int j = tid & 127, rg = tid >> 7;          // 8 groups x 8 rows
        float acc[8];
        float b = bc1[j];
        #pragma unroll
        for (int r = 0; r < 8; ++r) acc[r] = b;
        #pragma unroll 4
        for (int k = 0; k < 256; ++k) {
            float w = Wc1[k * H2_ + j];
            #pragma unroll
            for (int r = 0; r < 8; ++r) acc[r] += z0s[rg * 8 + r][k] * w;
        }
        float cs = 0.f, cq = 0.f;
        #pragma unroll
        for (int r = 0; r < 8; ++r) { cs += acc[r]; cq += acc[r] * acc[r]; }
        red_s[rg * 128 + j] = cs;
        red_q[rg * 128 + j] = cq;
        __syncthreads();
        if (tid < 128) {
            float s = 0.f, q = 0.f;
            #pragma unroll
            for (int g = 0; g < 8; ++g) { s += red_s[g * 128 + tid]; q += red_q[g * 128 + tid]; }
            float mu = s * (1.0f / NG);
            float var = q * (1.0f / NG) - mu * mu;
            float sc = gc1[tid] * rsqrtf(var + BN_EPS);
            scs[tid] = sc;
            shs[tid] = bec1[tid] - mu * sc;
        }
        __syncthreads();
        float sc = scs[j], sh = shs[j];
        #pragma unroll
        for (int r = 0; r < 8; ++r)
            es[rg * 8 + r][j] = fmaxf(acc[r] * sc + sh, 0.f);
    }
    __syncthreads();

    if (tid < NG * NC_) { // stage C: logits = z1 @ Wc2 + bc2
        int r2 = tid >> 1, c = tid & 1;
        float acc = bc2[c];
        #pragma unroll 4
        for (int k = 0; k < H2_; ++k) acc += es[r2][k] * Wc2[k * NC_ + c];
        logits[r2 * NC_ + c] = acc;
    }
}

// ---------------------------------------------------------------------------
extern "C" void kernel_launch(void* const* d_in, const int* in_sizes, int n_in,
                              void* d_out, int out_size, void* d_ws, size_t ws_size,
                              hipStream_t stream)
{
    const float* x    = (const float*)d_in[0];
    const int*   ei   = (const int*)d_in[1];
    const int*   batch= (const int*)d_in[2];
    const float* Wl0  = (const float*)d_in[3];
    const float* bl0  = (const float*)d_in[4];
    const float* Wr0  = (const float*)d_in[5];
    const float* g0   = (const float*)d_in[6];
    const float* be0  = (const float*)d_in[7];
    const float* Wl1  = (const float*)d_in[8];
    const float* bl1  = (const float*)d_in[9];
    const float* Wr1  = (const float*)d_in[10];
    const float* g1   = (const float*)d_in[11];
    const float* be1  = (const float*)d_in[12];
    const float* Wp0  = (const float*)d_in[13];
    const float* bp0  = (const float*)d_in[14];
    const float* Wp1  = (const float*)d_in[15];
    const float* bp1  = (const float*)d_in[16];
    const float* Wc0  = (const float*)d_in[17];
    const float* bc0  = (const float*)d_in[18];
    const float* gc0  = (const float*)d_in[19];
    const float* bec0 = (const float*)d_in[20];
    const float* Wc1  = (const float*)d_in[21];
    const float* bc1  = (const float*)d_in[22];
    const float* gc1  = (const float*)d_in[23];
    const float* bec1 = (const float*)d_in[24];
    const float* Wc2  = (const float*)d_in[25];
    const float* bc2  = (const float*)d_in[26];

    // ---- workspace layout (float units). Total ~36.04M fl = 137.5 MiB
    float* ws = (float*)d_ws;
    float* fs = ws;                              // 32768 small area
    float* ss0       = fs + 768;                 // 512 (scale0, shift0)
    float* ss1       = fs + 1280;                // 256 (scale1, shift1)
    float* pooled    = fs + 1536;                // 8192
    float* pcnt      = fs + 9728;                // 64
    float* emb       = fs + 9792;                // 8192

    unsigned short* wcomb0 = (unsigned short*)(ws + 32768);  // 98304 bf16
    unsigned short* wcomb1 = (unsigned short*)(ws + 81920);  // 98304 bf16

    int* deg    = (int*)(ws + 131072);           // 50000
    int* cursor = deg + 50000;                   // 50000
    int* ell    = cursor + 50000;                // 3,200,000 (PAD_=64 slots/node)

    unsigned short* h0b    = (unsigned short*)(ws + 3431072);   // 12.8M bf16
    unsigned short* xb     = (unsigned short*)(ws + 9831072);   // 6.4M bf16
    unsigned short* meanb0 = (unsigned short*)(ws + 13031072);  // 6.4M bf16
    unsigned short* meanb1 = xb;                 // reuse (12.8M bf16, overlays meanb0)
    float* t0  = ws + 16231072;                  // 12.8M f32
    float* t1  = t0;                             // 6.4M f32 (reuse)
    float* r1  = t0 + 6400000;                   // 6.4M f32 (reuse)
    unsigned short* r0b = (unsigned short*)(ws + 29031072);     // 12.8M bf16
    float* psS0 = ws + 35431072;                 // 782*256 = 200192
    float* psQ0 = psS0 + 200192;                 // 200192
    float* psS1 = psQ0 + 200192;                 // 782*128 = 100096
    float* psQ1 = psS1 + 100096;                 // 100096 (ends 36,031,648)

    float* logits_out = (float*)d_out;
    float* emb_out    = logits_out + NG * NC_;

    hipMemsetAsync(fs, 0, 32768 * sizeof(float), stream);
    hipMemsetAsync(deg, 0, 100000 * sizeof(int), stream);   // deg + cursor

    // ---- prep: ELL adjacency, bf16 x, swizzled weights ----
    degree_kernel<<<(N_EDGES + 255) / 256, 256, 0, stream>>>(ei, deg);
    fill_kernel<<<(N_EDGES + 255) / 256, 256, 0, stream>>>(ei, cursor, ell);
    conv_bf16_kernel<<<(N_NODES * D_IN / 4 + 255) / 256, 256, 0, stream>>>(
        x, xb, N_NODES * D_IN / 4);
    wswz_kernel<D_IN, D_IN, H1_><<<48, 256, 0, stream>>>(Wl0, Wr0, Wp0, wcomb0);
    wswz_kernel<H1_, H1_, H2_><<<48, 256, 0, stream>>>(Wl1, Wr1, Wp1, wcomb1);

    // ---- layer 0 ----
    gather_mean_bf16_kernel<D_IN><<<(N_NODES + 7) / 8, 256, 0, stream>>>(
        xb, deg, ell, meanb0);
    gemm_mfma_kernel<D_IN, D_IN, H1_, true><<<NBLK_G, 256, 0, stream>>>(
        meanb0, xb, wcomb0, bl0, bp0, t0, r0b, psS0, psQ0);
    bn_finalize<H1_><<<1, H1_, 0, stream>>>(psS0, psQ0, g0, be0, ss0, ss0 + 256);
    ew0_kernel<<<(N_NODES * H1_ / 4 + 255) / 256, 256, 0, stream>>>(
        (const float4*)t0, (const ushort4*)r0b, ss0, ss0 + 256, (ushort4*)h0b);

    // ---- layer 1 ----
    gather_mean_bf16_kernel<H1_><<<(N_NODES + 3) / 4, 256, 0, stream>>>(
        h0b, deg, ell, meanb1);
    gemm_mfma_kernel<H1_, H1_, H2_, false><<<NBLK_G, 256, 0, stream>>>(
        meanb1, h0b, wcomb1, bl1, bp1, t1, r1, psS1, psQ1);
    bn_finalize<H2_><<<1, H2_, 0, stream>>>(psS1, psQ1, g1, be1, ss1, ss1 + 128);
    ew1_pool_kernel<<<(N_NODES + 63) / 64, H2_, 0, stream>>>(
        t1, r1, ss1, ss1 + 128, batch, pooled, pcnt);

    // ---- pooling + classifier ----
    pool_fin_kernel<<<32, 256, 0, stream>>>(pooled, pcnt, emb, emb_out);
    classifier_kernel<<<1, 1024, 0, stream>>>(
        emb, Wc0, bc0, gc0, bec0, Wc1, bc1, gc1, bec1, Wc2, bc2, logits_out);
}

// Round 12
// 567.819 us; speedup vs baseline: 1.3846x; 1.3846x over previous
//
#include <hip/hip_runtime.h>
#include <hip/hip_bf16.h>
#include <math.h>

#define N_NODES 50000
#define N_EDGES 800000
#define D_IN    128
#define H1_     256
#define H2_     128
#define NG      64
#define NC_     2
#define BN_EPS  1e-5f
#define PAD_    64      // ELL slots per node; deg~Poisson(16), P(deg>64)~2e-18
#define NBLK_G  782     // gemm grid blocks = ceil(50000/64)

typedef __attribute__((ext_vector_type(8))) short bf16x8;
typedef __attribute__((ext_vector_type(4))) float f32x4;

__device__ __forceinline__ float bf2f(unsigned short u) {
    unsigned int v = ((unsigned int)u) << 16;
    return __uint_as_float(v);
}
__device__ __forceinline__ unsigned short f2bf(float f) {
    __hip_bfloat16 h = __float2bfloat16(f);
    return *reinterpret_cast<unsigned short*>(&h);
}

// ---------------------------------------------------------------------------
// padded-ELL adjacency build (no prefix scan needed)
// ---------------------------------------------------------------------------
__global__ void degree_kernel(const int* __restrict__ ei, int* __restrict__ deg)
{
    int e = blockIdx.x * 256 + threadIdx.x;
    if (e < N_EDGES) atomicAdd(&deg[ei[N_EDGES + e]], 1);
}

__global__ void fill_kernel(const int* __restrict__ ei, int* __restrict__ cursor,
                            int* __restrict__ ell)
{
    int e = blockIdx.x * 256 + threadIdx.x;
    if (e < N_EDGES) {
        int d = ei[N_EDGES + e];
        int off = atomicAdd(&cursor[d], 1);
        if (off < PAD_) ell[d * PAD_ + off] = ei[e];   // clamp: memory safety
    }
}

// ---------------------------------------------------------------------------
// f32 -> bf16 convert (4 elems/thread)
// ---------------------------------------------------------------------------
__global__ void conv_bf16_kernel(const float* __restrict__ in,
                                 unsigned short* __restrict__ out, int n4)
{
    int i = blockIdx.x * 256 + threadIdx.x;
    if (i < n4) {
        float4 v = ((const float4*)in)[i];
        ushort4 o;
        o.x = f2bf(v.x); o.y = f2bf(v.y); o.z = f2bf(v.z); o.w = f2bf(v.w);
        ((ushort4*)out)[i] = o;
    }
}

// ---------------------------------------------------------------------------
// weight swizzle into per-nt-contiguous MFMA fragment slices, f32 -> bf16.
// slice nt = [NKT_T frags of [Wl;Wr] | NKT_R frags of Wp]
// fragment element j = W[kt*32 + (lane>>4)*8 + j][nt*16 + (lane&15)]
// ---------------------------------------------------------------------------
template<int K1, int K2, int HOUT>
__global__ void wswz_kernel(const float* __restrict__ Wl, const float* __restrict__ Wr,
                            const float* __restrict__ Wp,
                            unsigned short* __restrict__ wcomb)
{
    constexpr int NKT_T = (K1 + K2) / 32;
    constexpr int NKT_R = K2 / 32;
    constexpr int F = NKT_T + NKT_R;
    constexpr int NNT = HOUT / 16;
    int idx = blockIdx.x * 256 + threadIdx.x;   // fragment-lane id
    if (idx >= NNT * F * 64) return;
    int lane = idx & 63, fi = idx >> 6;
    int f = fi % F, nt = fi / F;
    int col = nt * 16 + (lane & 15);
    int kq8 = (lane >> 4) * 8;
    unsigned short o[8];
    if (f < NKT_T) {
        int k0 = f * 32 + kq8;
        #pragma unroll
        for (int j = 0; j < 8; ++j) {
            int k = k0 + j;
            float v = (k < K1) ? Wl[(size_t)k * HOUT + col]
                               : Wr[(size_t)(k - K1) * HOUT + col];
            o[j] = f2bf(v);
        }
    } else {
        int k0 = (f - NKT_T) * 32 + kq8;
        #pragma unroll
        for (int j = 0; j < 8; ++j)
            o[j] = f2bf(Wp[(size_t)(k0 + j) * HOUT + col]);
    }
    ushort4 lo, hi;
    lo.x = o[0]; lo.y = o[1]; lo.z = o[2]; lo.w = o[3];
    hi.x = o[4]; hi.y = o[5]; hi.z = o[6]; hi.w = o[7];
    ((ushort4*)wcomb)[idx * 2]     = lo;
    ((ushort4*)wcomb)[idx * 2 + 1] = hi;
}

// ---------------------------------------------------------------------------
// gather-mean from bf16 features over padded-ELL adjacency
// ---------------------------------------------------------------------------
template<int D>
__global__ __launch_bounds__(256) void gather_mean_bf16_kernel(
    const unsigned short* __restrict__ xb, const int* __restrict__ deg,
    const int* __restrict__ ell, unsigned short* __restrict__ mean)
{
    constexpr int GT = D / 4;         // lanes per node, 4 bf16 (8B) per lane
    constexpr int NGRP = 256 / GT;
    int grp = threadIdx.x / GT;
    int t   = threadIdx.x % GT;
    int n = blockIdx.x * NGRP + grp;
    if (n >= N_NODES) return;
    int dn = deg[n];
    int cnt = min(dn, PAD_);
    const int* lst = ell + n * PAD_;
    const ushort4* xv = (const ushort4*)xb;
    float a0 = 0.f, a1 = 0.f, a2 = 0.f, a3 = 0.f;
    int e = 0;
    for (; e + 1 < cnt; e += 2) {
        int s0 = lst[e], s1 = lst[e + 1];
        ushort4 v0 = xv[(size_t)s0 * GT + t];
        ushort4 v1 = xv[(size_t)s1 * GT + t];
        a0 += bf2f(v0.x) + bf2f(v1.x);
        a1 += bf2f(v0.y) + bf2f(v1.y);
        a2 += bf2f(v0.z) + bf2f(v1.z);
        a3 += bf2f(v0.w) + bf2f(v1.w);
    }
    if (e < cnt) {
        int s0 = lst[e];
        ushort4 v0 = xv[(size_t)s0 * GT + t];
        a0 += bf2f(v0.x); a1 += bf2f(v0.y); a2 += bf2f(v0.z); a3 += bf2f(v0.w);
    }
    float inv = 1.0f / fmaxf((float)dn, 1.0f);
    ushort4 o;
    o.x = f2bf(a0 * inv); o.y = f2bf(a1 * inv);
    o.z = f2bf(a2 * inv); o.w = f2bf(a3 * inv);
    ((ushort4*)mean)[(size_t)n * GT + t] = o;
}

// ---------------------------------------------------------------------------
// MFMA GEMM (direct global weight reads) + fused epilogue.
// BN column stats: per-block PARTIAL SUMS (plain stores, contention-free);
// reduction happens in the parallel bn_finalize. No global atomics here.
// C/D: col=lane&15, row=(lane>>4)*4+reg  [m89]
// ---------------------------------------------------------------------------
template<int K1, int K2, int HOUT, bool R_BF16>
__global__ __launch_bounds__(256) void gemm_mfma_kernel(
    const unsigned short* __restrict__ meanb,   // [N][K1] bf16
    const unsigned short* __restrict__ selfb,   // [N][K2] bf16
    const unsigned short* __restrict__ wcomb,   // per-nt weight slices
    const float* __restrict__ bl, const float* __restrict__ bp,
    float* __restrict__ tout,
    void* __restrict__ rout,
    float* __restrict__ psS, float* __restrict__ psQ)
{
    constexpr int NKT_T = (K1 + K2) / 32;
    constexpr int NKT_R = K2 / 32;
    constexpr int NKT_M = K1 / 32;
    constexpr int F     = NKT_T + NKT_R;
    constexpr int NNT   = HOUT / 16;
    __shared__ float sred_s[4][HOUT];
    __shared__ float sred_q[4][HOUT];

    int tid = threadIdx.x;
    int w = tid >> 6, lane = tid & 63;
    int lm = lane & 15, kq = lane >> 4;
    int arow = blockIdx.x * 64 + w * 16 + lm;
    int lrow = (arow < N_NODES) ? arow : (N_NODES - 1);

    // ---- A fragments (registers) ----
    bf16x8 af[NKT_T];
    {
        const unsigned short* mrow = meanb + (size_t)lrow * K1 + kq * 8;
        const unsigned short* srow = selfb + (size_t)lrow * K2 + kq * 8;
        #pragma unroll
        for (int kt = 0; kt < NKT_M; ++kt)
            af[kt] = *(const bf16x8*)(mrow + kt * 32);
        #pragma unroll
        for (int kt = 0; kt < NKT_R; ++kt)
            af[NKT_M + kt] = *(const bf16x8*)(srow + kt * 32);
    }

    int orow0 = blockIdx.x * 64 + w * 16 + kq * 4;
    f32x4 tv[NNT];
    float ssq[4] = {0.f, 0.f, 0.f, 0.f};

    #pragma unroll
    for (int nt = 0; nt < NNT; ++nt) {
        // t = [mean|x] @ [Wl;Wr]
        f32x4 acc = {0.f, 0.f, 0.f, 0.f};
        #pragma unroll
        for (int kt = 0; kt < NKT_T; ++kt) {
            bf16x8 bw = *(const bf16x8*)(wcomb + ((size_t)(nt * F + kt) * 64 + lane) * 8);
            acc = __builtin_amdgcn_mfma_f32_16x16x32_bf16(af[kt], bw, acc, 0, 0, 0);
        }
        float blj = bl[nt * 16 + lm];
        #pragma unroll
        for (int r = 0; r < 4; ++r) {
            acc[r] += blj;
            ssq[r] += acc[r] * acc[r];
        }
        tv[nt] = acc;

        // r = x @ Wp  (store immediately, fire-and-forget)
        f32x4 racc = {0.f, 0.f, 0.f, 0.f};
        #pragma unroll
        for (int kt = 0; kt < NKT_R; ++kt) {
            bf16x8 bw = *(const bf16x8*)(wcomb + ((size_t)(nt * F + NKT_T + kt) * 64 + lane) * 8);
            racc = __builtin_amdgcn_mfma_f32_16x16x32_bf16(af[NKT_M + kt], bw, racc, 0, 0, 0);
        }
        float bpj = bp[nt * 16 + lm];
        #pragma unroll
        for (int r = 0; r < 4; ++r) {
            int orow = orow0 + r;
            if (orow < N_NODES) {
                float v = racc[r] + bpj;
                if (R_BF16)
                    ((unsigned short*)rout)[(size_t)orow * HOUT + nt * 16 + lm] = f2bf(v);
                else
                    ((float*)rout)[(size_t)orow * HOUT + nt * 16 + lm] = v;
            }
        }
    }

    // ---- row L2-norm: reduce ssq over the 16 col-lanes ----
    #pragma unroll
    for (int off = 1; off <= 8; off <<= 1)
        #pragma unroll
        for (int r = 0; r < 4; ++r)
            ssq[r] += __shfl_xor(ssq[r], off);
    float inv[4];
    #pragma unroll
    for (int r = 0; r < 4; ++r)
        inv[r] = 1.0f / fmaxf(sqrtf(ssq[r]), 1e-12f);

    // ---- normalize, store t, accumulate BN column stats ----
    #pragma unroll
    for (int nt = 0; nt < NNT; ++nt) {
        float cs = 0.f, cq = 0.f;
        #pragma unroll
        for (int r = 0; r < 4; ++r) {
            int orow = orow0 + r;
            float v = tv[nt][r] * inv[r];
            if (orow < N_NODES) {
                tout[(size_t)orow * HOUT + nt * 16 + lm] = v;
                cs += v; cq += v * v;
            }
        }
        cs += __shfl_xor(cs, 16); cs += __shfl_xor(cs, 32);
        cq += __shfl_xor(cq, 16); cq += __shfl_xor(cq, 32);
        if (kq == 0) {
            sred_s[w][nt * 16 + lm] = cs;
            sred_q[w][nt * 16 + lm] = cq;
        }
    }
    __syncthreads();
    if (tid < HOUT) {
        float s = sred_s[0][tid] + sred_s[1][tid] + sred_s[2][tid] + sred_s[3][tid];
        float q = sred_q[0][tid] + sred_q[1][tid] + sred_q[2][tid] + sred_q[3][tid];
        psS[(size_t)blockIdx.x * HOUT + tid] = s;   // plain store, no atomic
        psQ[(size_t)blockIdx.x * HOUT + tid] = q;
    }
}

// ---------------------------------------------------------------------------
// PARALLEL reduce of per-block partials -> BN scale/shift.
// grid = H blocks (one column each), 256 threads stride over the 782 blocks.
// ---------------------------------------------------------------------------
template<int H>
__global__ __launch_bounds__(256) void bn_finalize(
    const float* __restrict__ psS, const float* __restrict__ psQ,
    const float* __restrict__ g, const float* __restrict__ be,
    float* __restrict__ scale, float* __restrict__ shift)
{
    __shared__ float ws_[4], wq_[4];
    int j = blockIdx.x;
    int tid = threadIdx.x;
    int wv = tid >> 6, lane = tid & 63;
    float s = 0.f, q = 0.f;
    for (int b = tid; b < NBLK_G; b += 256) {
        s += psS[(size_t)b * H + j];
        q += psQ[(size_t)b * H + j];
    }
    #pragma unroll
    for (int off = 32; off >= 1; off >>= 1) {
        s += __shfl_xor(s, off);
        q += __shfl_xor(q, off);
    }
    if (lane == 0) { ws_[wv] = s; wq_[wv] = q; }
    __syncthreads();
    if (tid == 0) {
        s = ws_[0] + ws_[1] + ws_[2] + ws_[3];
        q = wq_[0] + wq_[1] + wq_[2] + wq_[3];
        float mu = s / (float)N_NODES;
        float var = q / (float)N_NODES - mu * mu;
        float sc = g[j] * rsqrtf(var + BN_EPS);
        scale[j] = sc;
        shift[j] = be[j] - mu * sc;
    }
}

// ---------------------------------------------------------------------------
// layer 0 epilogue: h0b = bf16( relu(t*scale+shift) + r0b )
// ---------------------------------------------------------------------------
__global__ void ew0_kernel(const float4* __restrict__ t, const ushort4* __restrict__ rb,
                           const float* __restrict__ scale, const float* __restrict__ shift,
                           ushort4* __restrict__ h0b)
{
    int gid = blockIdx.x * 256 + threadIdx.x;
    if (gid >= N_NODES * H1_ / 4) return;
    int j4 = gid & (H1_ / 4 - 1);
    float4 sc = *(const float4*)(scale + j4 * 4);
    float4 sh = *(const float4*)(shift + j4 * 4);
    float4 tv = t[gid];
    ushort4 rv = rb[gid];
    ushort4 hb;
    hb.x = f2bf(fmaxf(tv.x * sc.x + sh.x, 0.f) + bf2f(rv.x));
    hb.y = f2bf(fmaxf(tv.y * sc.y + sh.y, 0.f) + bf2f(rv.y));
    hb.z = f2bf(fmaxf(tv.z * sc.z + sh.z, 0.f) + bf2f(rv.z));
    hb.w = f2bf(fmaxf(tv.w * sc.w + sh.w, 0.f) + bf2f(rv.w));
    h0b[gid] = hb;
}

// ---------------------------------------------------------------------------
// layer 1 epilogue fused with mean-pool scatter (batch sorted -> run-length)
// ---------------------------------------------------------------------------
__global__ __launch_bounds__(H2_) void ew1_pool_kernel(
    const float* __restrict__ t, const float* __restrict__ r,
    const float* __restrict__ scale, const float* __restrict__ shift,
    const int* __restrict__ batch,
    float* __restrict__ pooled, float* __restrict__ pcnt)
{
    int j = threadIdx.x;
    int n0 = blockIdx.x * 64;
    int nend = min(n0 + 64, N_NODES);
    float acc = 0.f, cacc = 0.f;
    int run = -1;
    float sc = scale[j], sh = shift[j];
    for (int n = n0; n < nend; ++n) {
        int b = batch[n];
        if (b != run) {
            if (run >= 0) {
                atomicAdd(&pooled[run * H2_ + j], acc);
                if (j == 0) atomicAdd(&pcnt[run], cacc);
            }
            run = b; acc = 0.f; cacc = 0.f;
        }
        float v = t[(size_t)n * H2_ + j] * sc + sh;
        v = fmaxf(v, 0.f) + r[(size_t)n * H2_ + j];
        acc += v;
        cacc += 1.f;
    }
    if (run >= 0) {
        atomicAdd(&pooled[run * H2_ + j], acc);
        if (j == 0) atomicAdd(&pcnt[run], cacc);
    }
}

// ---------------------------------------------------------------------------
__global__ void pool_fin_kernel(const float* __restrict__ pooled, const float* __restrict__ pcnt,
                                float* __restrict__ emb, float* __restrict__ emb_out)
{
    int gid = blockIdx.x * blockDim.x + threadIdx.x;
    if (gid < NG * H2_) {
        int g = gid >> 7;
        float v = pooled[gid] / fmaxf(pcnt[g], 1.0f);
        emb[gid] = v;
        emb_out[gid] = v;
    }
}

// ---------------------------------------------------------------------------
// classifier MLP, single block, 1024 threads (16 waves for latency hiding)
// ---------------------------------------------------------------------------
__global__ __launch_bounds__(1024) void classifier_kernel(
    const float* __restrict__ emb,
    const float* __restrict__ Wc0, const float* __restrict__ bc0,
    const float* __restrict__ gc0, const float* __restrict__ bec0,
    const float* __restrict__ Wc1, const float* __restrict__ bc1,
    const float* __restrict__ gc1, const float* __restrict__ bec1,
    const float* __restrict__ Wc2, const float* __restrict__ bc2,
    float* __restrict__ logits)
{
    __shared__ float es[NG][H2_];     // 32 KB: emb, later z1
    __shared__ float z0s[NG][256];    // 64 KB
    __shared__ float red_s[1024];     // 4 KB
    __shared__ float red_q[1024];     // 4 KB
    __shared__ float scs[256], shs[256];
    int tid = threadIdx.x;
    for (int i = tid; i < NG * H2_; i += 1024) es[i >> 7][i & 127] = emb[i];
    __syncthreads();

    { // stage A: z0 = relu(bn(emb @ Wc0 + bc0))  [64x128 @ 128x256]
        int j = tid & 255, rg = tid >> 8;          // 4 groups x 16 rows
        float acc[16];
        float b = bc0[j];
        #pragma unroll
        for (int r = 0; r < 16; ++r) acc[r] = b;
        #pragma unroll 4
        for (int k = 0; k < H2_; ++k) {
            float w = Wc0[k * 256 + j];
            #pragma unroll
            for (int r = 0; r < 16; ++r) acc[r] += es[rg * 16 + r][k] * w;
        }
        float cs = 0.f, cq = 0.f;
        #pragma unroll
        for (int r = 0; r < 16; ++r) { cs += acc[r]; cq += acc[r] * acc[r]; }
        red_s[rg * 256 + j] = cs;
        red_q[rg * 256 + j] = cq;
        __syncthreads();
        if (tid < 256) {
            float s = red_s[tid] + red_s[256 + tid] + red_s[512 + tid] + red_s[768 + tid];
            float q = red_q[tid] + red_q[256 + tid] + red_q[512 + tid] + red_q[768 + tid];
            float mu = s * (1.0f / NG);
            float var = q * (1.0f / NG) - mu * mu;
            float sc = gc0[tid] * rsqrtf(var + BN_EPS);
            scs[tid] = sc;
            shs[tid] = bec0[tid] - mu * sc;
        }
        __syncthreads();
        float sc = scs[j], sh = shs[j];
        #pragma unroll
        for (int r = 0; r < 16; ++r)
            z0s[rg * 16 + r][j] = fmaxf(acc[r] * sc + sh, 0.f);
    }
    __syncthreads();

    { // stage B: z1 = relu(bn(z0 @ Wc1 + bc1))  [64x256 @ 256x128] -> es
        int j = tid & 127, rg = tid >> 7;          // 8 groups x 8 rows
        float acc[8];
        float b = bc1[j];
        #pragma unroll
        for (int r = 0; r < 8; ++r) acc[r] = b;
        #pragma unroll 4
        for (int k = 0; k < 256; ++k) {
            float w = Wc1[k * H2_ + j];
            #pragma unroll
            for (int r = 0; r < 8; ++r) acc[r] += z0s[rg * 8 + r][k] * w;
        }
        float cs = 0.f, cq = 0.f;
        #pragma unroll
        for (int r = 0; r < 8; ++r) { cs += acc[r]; cq += acc[r] * acc[r]; }
        red_s[rg * 128 + j] = cs;
        red_q[rg * 128 + j] = cq;
        __syncthreads();
        if (tid < 128) {
            float s = 0.f, q = 0.f;
            #pragma unroll
            for (int g = 0; g < 8; ++g) { s += red_s[g * 128 + tid]; q += red_q[g * 128 + tid]; }
            float mu = s * (1.0f / NG);
            float var = q * (1.0f / NG) - mu * mu;
            float sc = gc1[tid] * rsqrtf(var + BN_EPS);
            scs[tid] = sc;
            shs[tid] = bec1[tid] - mu * sc;
        }
        __syncthreads();
        float sc = scs[j], sh = shs[j];
        #pragma unroll
        for (int r = 0; r < 8; ++r)
            es[rg * 8 + r][j] = fmaxf(acc[r] * sc + sh, 0.f);
    }
    __syncthreads();

    if (tid < NG * NC_) { // stage C: logits = z1 @ Wc2 + bc2
        int r2 = tid >> 1, c = tid & 1;
        float acc = bc2[c];
        #pragma unroll 4
        for (int k = 0; k < H2_; ++k) acc += es[r2][k] * Wc2[k * NC_ + c];
        logits[r2 * NC_ + c] = acc;
    }
}

// ---------------------------------------------------------------------------
extern "C" void kernel_launch(void* const* d_in, const int* in_sizes, int n_in,
                              void* d_out, int out_size, void* d_ws, size_t ws_size,
                              hipStream_t stream)
{
    const float* x    = (const float*)d_in[0];
    const int*   ei   = (const int*)d_in[1];
    const int*   batch= (const int*)d_in[2];
    const float* Wl0  = (const float*)d_in[3];
    const float* bl0  = (const float*)d_in[4];
    const float* Wr0  = (const float*)d_in[5];
    const float* g0   = (const float*)d_in[6];
    const float* be0  = (const float*)d_in[7];
    const float* Wl1  = (const float*)d_in[8];
    const float* bl1  = (const float*)d_in[9];
    const float* Wr1  = (const float*)d_in[10];
    const float* g1   = (const float*)d_in[11];
    const float* be1  = (const float*)d_in[12];
    const float* Wp0  = (const float*)d_in[13];
    const float* bp0  = (const float*)d_in[14];
    const float* Wp1  = (const float*)d_in[15];
    const float* bp1  = (const float*)d_in[16];
    const float* Wc0  = (const float*)d_in[17];
    const float* bc0  = (const float*)d_in[18];
    const float* gc0  = (const float*)d_in[19];
    const float* bec0 = (const float*)d_in[20];
    const float* Wc1  = (const float*)d_in[21];
    const float* bc1  = (const float*)d_in[22];
    const float* gc1  = (const float*)d_in[23];
    const float* bec1 = (const float*)d_in[24];
    const float* Wc2  = (const float*)d_in[25];
    const float* bc2  = (const float*)d_in[26];

    // ---- workspace layout (float units). Total ~36.04M fl = 137.5 MiB
    float* ws = (float*)d_ws;
    float* fs = ws;                              // 32768 small area
    float* ss0       = fs + 768;                 // 512 (scale0, shift0)
    float* ss1       = fs + 1280;                // 256 (scale1, shift1)
    float* pooled    = fs + 1536;                // 8192
    float* pcnt      = fs + 9728;                // 64
    float* emb       = fs + 9792;                // 8192

    unsigned short* wcomb0 = (unsigned short*)(ws + 32768);  // 98304 bf16
    unsigned short* wcomb1 = (unsigned short*)(ws + 81920);  // 98304 bf16

    int* deg    = (int*)(ws + 131072);           // 50000
    int* cursor = deg + 50000;                   // 50000
    int* ell    = cursor + 50000;                // 3,200,000 (PAD_=64 slots/node)

    unsigned short* h0b    = (unsigned short*)(ws + 3431072);   // 12.8M bf16
    unsigned short* xb     = (unsigned short*)(ws + 9831072);   // 6.4M bf16
    unsigned short* meanb0 = (unsigned short*)(ws + 13031072);  // 6.4M bf16
    unsigned short* meanb1 = xb;                 // reuse (12.8M bf16, overlays meanb0)
    float* t0  = ws + 16231072;                  // 12.8M f32
    float* t1  = t0;                             // 6.4M f32 (reuse)
    float* r1  = t0 + 6400000;                   // 6.4M f32 (reuse)
    unsigned short* r0b = (unsigned short*)(ws + 29031072);     // 12.8M bf16
    float* psS0 = ws + 35431072;                 // 782*256 = 200192
    float* psQ0 = psS0 + 200192;                 // 200192
    float* psS1 = psQ0 + 200192;                 // 782*128 = 100096
    float* psQ1 = psS1 + 100096;                 // 100096 (ends 36,031,648)

    float* logits_out = (float*)d_out;
    float* emb_out    = logits_out + NG * NC_;

    hipMemsetAsync(fs, 0, 32768 * sizeof(float), stream);
    hipMemsetAsync(deg, 0, 100000 * sizeof(int), stream);   // deg + cursor

    // ---- prep: ELL adjacency, bf16 x, swizzled weights ----
    degree_kernel<<<(N_EDGES + 255) / 256, 256, 0, stream>>>(ei, deg);
    fill_kernel<<<(N_EDGES + 255) / 256, 256, 0, stream>>>(ei, cursor, ell);
    conv_bf16_kernel<<<(N_NODES * D_IN / 4 + 255) / 256, 256, 0, stream>>>(
        x, xb, N_NODES * D_IN / 4);
    wswz_kernel<D_IN, D_IN, H1_><<<48, 256, 0, stream>>>(Wl0, Wr0, Wp0, wcomb0);
    wswz_kernel<H1_, H1_, H2_><<<48, 256, 0, stream>>>(Wl1, Wr1, Wp1, wcomb1);

    // ---- layer 0 ----
    gather_mean_bf16_kernel<D_IN><<<(N_NODES + 7) / 8, 256, 0, stream>>>(
        xb, deg, ell, meanb0);
    gemm_mfma_kernel<D_IN, D_IN, H1_, true><<<NBLK_G, 256, 0, stream>>>(
        meanb0, xb, wcomb0, bl0, bp0, t0, r0b, psS0, psQ0);
    bn_finalize<H1_><<<H1_, 256, 0, stream>>>(psS0, psQ0, g0, be0, ss0, ss0 + 256);
    ew0_kernel<<<(N_NODES * H1_ / 4 + 255) / 256, 256, 0, stream>>>(
        (const float4*)t0, (const ushort4*)r0b, ss0, ss0 + 256, (ushort4*)h0b);

    // ---- layer 1 ----
    gather_mean_bf16_kernel<H1_><<<(N_NODES + 3) / 4, 256, 0, stream>>>(
        h0b, deg, ell, meanb1);
    gemm_mfma_kernel<H1_, H1_, H2_, false><<<NBLK_G, 256, 0, stream>>>(
        meanb1, h0b, wcomb1, bl1, bp1, t1, r1, psS1, psQ1);
    bn_finalize<H2_><<<H2_, 256, 0, stream>>>(psS1, psQ1, g1, be1, ss1, ss1 + 128);
    ew1_pool_kernel<<<(N_NODES + 63) / 64, H2_, 0, stream>>>(
        t1, r1, ss1, ss1 + 128, batch, pooled, pcnt);

    // ---- pooling + classifier ----
    pool_fin_kernel<<<32, 256, 0, stream>>>(pooled, pcnt, emb, emb_out);
    classifier_kernel<<<1, 1024, 0, stream>>>(
        emb, Wc0, bc0, gc0, bec0, Wc1, bc1, gc1, bec1, Wc2, bc2, logits_out);
}

// Round 13
// 547.819 us; speedup vs baseline: 1.4352x; 1.0365x over previous
//
#include <hip/hip_runtime.h>
#include <hip/hip_bf16.h>
#include <math.h>

#define N_NODES 50000
#define N_EDGES 800000
#define D_IN    128
#define H1_     256
#define H2_     128
#define NG      64
#define NC_     2
#define BN_EPS  1e-5f
#define PAD_    64      // ELL slots per node; deg~Poisson(16), P(deg>64)~2e-18
#define NBLK_G  782     // gemm grid blocks = ceil(50000/64)

typedef __attribute__((ext_vector_type(8))) short bf16x8;
typedef __attribute__((ext_vector_type(4))) float f32x4;

__device__ __forceinline__ float bf2f(unsigned short u) {
    unsigned int v = ((unsigned int)u) << 16;
    return __uint_as_float(v);
}
__device__ __forceinline__ unsigned short f2bf(float f) {
    __hip_bfloat16 h = __float2bfloat16(f);
    return *reinterpret_cast<unsigned short*>(&h);
}

// ---------------------------------------------------------------------------
// padded-ELL adjacency build (no prefix scan needed)
// ---------------------------------------------------------------------------
__global__ void degree_kernel(const int* __restrict__ ei, int* __restrict__ deg)
{
    int e = blockIdx.x * 256 + threadIdx.x;
    if (e < N_EDGES) atomicAdd(&deg[ei[N_EDGES + e]], 1);
}

__global__ void fill_kernel(const int* __restrict__ ei, int* __restrict__ cursor,
                            int* __restrict__ ell)
{
    int e = blockIdx.x * 256 + threadIdx.x;
    if (e < N_EDGES) {
        int d = ei[N_EDGES + e];
        int off = atomicAdd(&cursor[d], 1);
        if (off < PAD_) ell[d * PAD_ + off] = ei[e];   // clamp: memory safety
    }
}

// ---------------------------------------------------------------------------
// f32 -> bf16 convert (4 elems/thread)
// ---------------------------------------------------------------------------
__global__ void conv_bf16_kernel(const float* __restrict__ in,
                                 unsigned short* __restrict__ out, int n4)
{
    int i = blockIdx.x * 256 + threadIdx.x;
    if (i < n4) {
        float4 v = ((const float4*)in)[i];
        ushort4 o;
        o.x = f2bf(v.x); o.y = f2bf(v.y); o.z = f2bf(v.z); o.w = f2bf(v.w);
        ((ushort4*)out)[i] = o;
    }
}

// ---------------------------------------------------------------------------
// weight swizzle into per-nt-contiguous MFMA fragment slices, f32 -> bf16.
// slice nt = [NKT_T frags of [Wl;Wr] | NKT_R frags of Wp]
// fragment element j = W[kt*32 + (lane>>4)*8 + j][nt*16 + (lane&15)]
// ---------------------------------------------------------------------------
template<int K1, int K2, int HOUT>
__global__ void wswz_kernel(const float* __restrict__ Wl, const float* __restrict__ Wr,
                            const float* __restrict__ Wp,
                            unsigned short* __restrict__ wcomb)
{
    constexpr int NKT_T = (K1 + K2) / 32;
    constexpr int NKT_R = K2 / 32;
    constexpr int F = NKT_T + NKT_R;
    constexpr int NNT = HOUT / 16;
    int idx = blockIdx.x * 256 + threadIdx.x;   // fragment-lane id
    if (idx >= NNT * F * 64) return;
    int lane = idx & 63, fi = idx >> 6;
    int f = fi % F, nt = fi / F;
    int col = nt * 16 + (lane & 15);
    int kq8 = (lane >> 4) * 8;
    unsigned short o[8];
    if (f < NKT_T) {
        int k0 = f * 32 + kq8;
        #pragma unroll
        for (int j = 0; j < 8; ++j) {
            int k = k0 + j;
            float v = (k < K1) ? Wl[(size_t)k * HOUT + col]
                               : Wr[(size_t)(k - K1) * HOUT + col];
            o[j] = f2bf(v);
        }
    } else {
        int k0 = (f - NKT_T) * 32 + kq8;
        #pragma unroll
        for (int j = 0; j < 8; ++j)
            o[j] = f2bf(Wp[(size_t)(k0 + j) * HOUT + col]);
    }
    ushort4 lo, hi;
    lo.x = o[0]; lo.y = o[1]; lo.z = o[2]; lo.w = o[3];
    hi.x = o[4]; hi.y = o[5]; hi.z = o[6]; hi.w = o[7];
    ((ushort4*)wcomb)[idx * 2]     = lo;
    ((ushort4*)wcomb)[idx * 2 + 1] = hi;
}

// ---------------------------------------------------------------------------
// gather-mean from bf16 features over padded-ELL adjacency
// ---------------------------------------------------------------------------
template<int D>
__global__ __launch_bounds__(256) void gather_mean_bf16_kernel(
    const unsigned short* __restrict__ xb, const int* __restrict__ deg,
    const int* __restrict__ ell, unsigned short* __restrict__ mean)
{
    constexpr int GT = D / 4;         // lanes per node, 4 bf16 (8B) per lane
    constexpr int NGRP = 256 / GT;
    int grp = threadIdx.x / GT;
    int t   = threadIdx.x % GT;
    int n = blockIdx.x * NGRP + grp;
    if (n >= N_NODES) return;
    int dn = deg[n];
    int cnt = min(dn, PAD_);
    const int* lst = ell + n * PAD_;
    const ushort4* xv = (const ushort4*)xb;
    float a0 = 0.f, a1 = 0.f, a2 = 0.f, a3 = 0.f;
    int e = 0;
    for (; e + 1 < cnt; e += 2) {
        int s0 = lst[e], s1 = lst[e + 1];
        ushort4 v0 = xv[(size_t)s0 * GT + t];
        ushort4 v1 = xv[(size_t)s1 * GT + t];
        a0 += bf2f(v0.x) + bf2f(v1.x);
        a1 += bf2f(v0.y) + bf2f(v1.y);
        a2 += bf2f(v0.z) + bf2f(v1.z);
        a3 += bf2f(v0.w) + bf2f(v1.w);
    }
    if (e < cnt) {
        int s0 = lst[e];
        ushort4 v0 = xv[(size_t)s0 * GT + t];
        a0 += bf2f(v0.x); a1 += bf2f(v0.y); a2 += bf2f(v0.z); a3 += bf2f(v0.w);
    }
    float inv = 1.0f / fmaxf((float)dn, 1.0f);
    ushort4 o;
    o.x = f2bf(a0 * inv); o.y = f2bf(a1 * inv);
    o.z = f2bf(a2 * inv); o.w = f2bf(a3 * inv);
    ((ushort4*)mean)[(size_t)n * GT + t] = o;
}

// ---------------------------------------------------------------------------
// MFMA GEMM + fused epilogue.
// __launch_bounds__(256,3): 3 waves/EU min -> VGPR cap ~170 (grid only needs
// 12 waves/CU for single-pass; default heuristic chose 76 VGPR and starved
// the load pipeline). Weight loads grouped 8-at-a-time into a register array
// before their MFMAs -> ~8 loads in flight instead of ~2.
// BN stats via per-block partial sums (no atomics). C/D: col=lane&15,
// row=(lane>>4)*4+reg  [m89]
// ---------------------------------------------------------------------------
template<int K1, int K2, int HOUT, bool R_BF16>
__global__ __launch_bounds__(256, 3) void gemm_mfma_kernel(
    const unsigned short* __restrict__ meanb,   // [N][K1] bf16
    const unsigned short* __restrict__ selfb,   // [N][K2] bf16
    const unsigned short* __restrict__ wcomb,   // per-nt weight slices
    const float* __restrict__ bl, const float* __restrict__ bp,
    float* __restrict__ tout,
    void* __restrict__ rout,
    float* __restrict__ psS, float* __restrict__ psQ)
{
    constexpr int NKT_T = (K1 + K2) / 32;
    constexpr int NKT_R = K2 / 32;
    constexpr int NKT_M = K1 / 32;
    constexpr int F     = NKT_T + NKT_R;
    constexpr int NNT   = HOUT / 16;
    __shared__ float sred_s[4][HOUT];
    __shared__ float sred_q[4][HOUT];

    int tid = threadIdx.x;
    int w = tid >> 6, lane = tid & 63;
    int lm = lane & 15, kq = lane >> 4;
    int arow = blockIdx.x * 64 + w * 16 + lm;
    int lrow = (arow < N_NODES) ? arow : (N_NODES - 1);

    // ---- A fragments (registers) ----
    bf16x8 af[NKT_T];
    {
        const unsigned short* mrow = meanb + (size_t)lrow * K1 + kq * 8;
        const unsigned short* srow = selfb + (size_t)lrow * K2 + kq * 8;
        #pragma unroll
        for (int kt = 0; kt < NKT_M; ++kt)
            af[kt] = *(const bf16x8*)(mrow + kt * 32);
        #pragma unroll
        for (int kt = 0; kt < NKT_R; ++kt)
            af[NKT_M + kt] = *(const bf16x8*)(srow + kt * 32);
    }

    int orow0 = blockIdx.x * 64 + w * 16 + kq * 4;
    f32x4 tv[NNT];
    float ssq[4] = {0.f, 0.f, 0.f, 0.f};

    #pragma unroll
    for (int nt = 0; nt < NNT; ++nt) {
        // t = [mean|x] @ [Wl;Wr] — load group of 8 frags, then MFMA group
        f32x4 acc = {0.f, 0.f, 0.f, 0.f};
        constexpr int TG = (NKT_T < 8) ? NKT_T : 8;
        #pragma unroll
        for (int kg = 0; kg < NKT_T; kg += TG) {
            bf16x8 bws[TG];
            #pragma unroll
            for (int i = 0; i < TG; ++i)
                bws[i] = *(const bf16x8*)(wcomb + ((size_t)(nt * F + kg + i) * 64 + lane) * 8);
            #pragma unroll
            for (int i = 0; i < TG; ++i)
                acc = __builtin_amdgcn_mfma_f32_16x16x32_bf16(af[kg + i], bws[i], acc, 0, 0, 0);
        }
        float blj = bl[nt * 16 + lm];
        #pragma unroll
        for (int r = 0; r < 4; ++r) {
            acc[r] += blj;
            ssq[r] += acc[r] * acc[r];
        }
        tv[nt] = acc;

        // r = x @ Wp — same grouped pattern, store immediately
        f32x4 racc = {0.f, 0.f, 0.f, 0.f};
        constexpr int RG = (NKT_R < 8) ? NKT_R : 8;
        #pragma unroll
        for (int kg = 0; kg < NKT_R; kg += RG) {
            bf16x8 bws[RG];
            #pragma unroll
            for (int i = 0; i < RG; ++i)
                bws[i] = *(const bf16x8*)(wcomb + ((size_t)(nt * F + NKT_T + kg + i) * 64 + lane) * 8);
            #pragma unroll
            for (int i = 0; i < RG; ++i)
                racc = __builtin_amdgcn_mfma_f32_16x16x32_bf16(af[NKT_M + kg + i], bws[i], racc, 0, 0, 0);
        }
        float bpj = bp[nt * 16 + lm];
        #pragma unroll
        for (int r = 0; r < 4; ++r) {
            int orow = orow0 + r;
            if (orow < N_NODES) {
                float v = racc[r] + bpj;
                if (R_BF16)
                    ((unsigned short*)rout)[(size_t)orow * HOUT + nt * 16 + lm] = f2bf(v);
                else
                    ((float*)rout)[(size_t)orow * HOUT + nt * 16 + lm] = v;
            }
        }
    }

    // ---- row L2-norm: reduce ssq over the 16 col-lanes ----
    #pragma unroll
    for (int off = 1; off <= 8; off <<= 1)
        #pragma unroll
        for (int r = 0; r < 4; ++r)
            ssq[r] += __shfl_xor(ssq[r], off);
    float inv[4];
    #pragma unroll
    for (int r = 0; r < 4; ++r)
        inv[r] = 1.0f / fmaxf(sqrtf(ssq[r]), 1e-12f);

    // ---- normalize, store t, accumulate BN column stats ----
    #pragma unroll
    for (int nt = 0; nt < NNT; ++nt) {
        float cs = 0.f, cq = 0.f;
        #pragma unroll
        for (int r = 0; r < 4; ++r) {
            int orow = orow0 + r;
            float v = tv[nt][r] * inv[r];
            if (orow < N_NODES) {
                tout[(size_t)orow * HOUT + nt * 16 + lm] = v;
                cs += v; cq += v * v;
            }
        }
        cs += __shfl_xor(cs, 16); cs += __shfl_xor(cs, 32);
        cq += __shfl_xor(cq, 16); cq += __shfl_xor(cq, 32);
        if (kq == 0) {
            sred_s[w][nt * 16 + lm] = cs;
            sred_q[w][nt * 16 + lm] = cq;
        }
    }
    __syncthreads();
    if (tid < HOUT) {
        float s = sred_s[0][tid] + sred_s[1][tid] + sred_s[2][tid] + sred_s[3][tid];
        float q = sred_q[0][tid] + sred_q[1][tid] + sred_q[2][tid] + sred_q[3][tid];
        psS[(size_t)blockIdx.x * HOUT + tid] = s;   // plain store, no atomic
        psQ[(size_t)blockIdx.x * HOUT + tid] = q;
    }
}

// ---------------------------------------------------------------------------
// PARALLEL reduce of per-block partials -> BN scale/shift.
// grid = H blocks (one column each), 256 threads stride over the 782 blocks.
// ---------------------------------------------------------------------------
template<int H>
__global__ __launch_bounds__(256) void bn_finalize(
    const float* __restrict__ psS, const float* __restrict__ psQ,
    const float* __restrict__ g, const float* __restrict__ be,
    float* __restrict__ scale, float* __restrict__ shift)
{
    __shared__ float ws_[4], wq_[4];
    int j = blockIdx.x;
    int tid = threadIdx.x;
    int wv = tid >> 6, lane = tid & 63;
    float s = 0.f, q = 0.f;
    for (int b = tid; b < NBLK_G; b += 256) {
        s += psS[(size_t)b * H + j];
        q += psQ[(size_t)b * H + j];
    }
    #pragma unroll
    for (int off = 32; off >= 1; off >>= 1) {
        s += __shfl_xor(s, off);
        q += __shfl_xor(q, off);
    }
    if (lane == 0) { ws_[wv] = s; wq_[wv] = q; }
    __syncthreads();
    if (tid == 0) {
        s = ws_[0] + ws_[1] + ws_[2] + ws_[3];
        q = wq_[0] + wq_[1] + wq_[2] + wq_[3];
        float mu = s / (float)N_NODES;
        float var = q / (float)N_NODES - mu * mu;
        float sc = g[j] * rsqrtf(var + BN_EPS);
        scale[j] = sc;
        shift[j] = be[j] - mu * sc;
    }
}

// ---------------------------------------------------------------------------
// layer 0 epilogue: h0b = bf16( relu(t*scale+shift) + r0b )
// ---------------------------------------------------------------------------
__global__ void ew0_kernel(const float4* __restrict__ t, const ushort4* __restrict__ rb,
                           const float* __restrict__ scale, const float* __restrict__ shift,
                           ushort4* __restrict__ h0b)
{
    int gid = blockIdx.x * 256 + threadIdx.x;
    if (gid >= N_NODES * H1_ / 4) return;
    int j4 = gid & (H1_ / 4 - 1);
    float4 sc = *(const float4*)(scale + j4 * 4);
    float4 sh = *(const float4*)(shift + j4 * 4);
    float4 tv = t[gid];
    ushort4 rv = rb[gid];
    ushort4 hb;
    hb.x = f2bf(fmaxf(tv.x * sc.x + sh.x, 0.f) + bf2f(rv.x));
    hb.y = f2bf(fmaxf(tv.y * sc.y + sh.y, 0.f) + bf2f(rv.y));
    hb.z = f2bf(fmaxf(tv.z * sc.z + sh.z, 0.f) + bf2f(rv.z));
    hb.w = f2bf(fmaxf(tv.w * sc.w + sh.w, 0.f) + bf2f(rv.w));
    h0b[gid] = hb;
}

// ---------------------------------------------------------------------------
// layer 1 epilogue fused with mean-pool scatter (batch sorted -> run-length)
// ---------------------------------------------------------------------------
__global__ __launch_bounds__(H2_) void ew1_pool_kernel(
    const float* __restrict__ t, const float* __restrict__ r,
    const float* __restrict__ scale, const float* __restrict__ shift,
    const int* __restrict__ batch,
    float* __restrict__ pooled, float* __restrict__ pcnt)
{
    int j = threadIdx.x;
    int n0 = blockIdx.x * 64;
    int nend = min(n0 + 64, N_NODES);
    float acc = 0.f, cacc = 0.f;
    int run = -1;
    float sc = scale[j], sh = shift[j];
    for (int n = n0; n < nend; ++n) {
        int b = batch[n];
        if (b != run) {
            if (run >= 0) {
                atomicAdd(&pooled[run * H2_ + j], acc);
                if (j == 0) atomicAdd(&pcnt[run], cacc);
            }
            run = b; acc = 0.f; cacc = 0.f;
        }
        float v = t[(size_t)n * H2_ + j] * sc + sh;
        v = fmaxf(v, 0.f) + r[(size_t)n * H2_ + j];
        acc += v;
        cacc += 1.f;
    }
    if (run >= 0) {
        atomicAdd(&pooled[run * H2_ + j], acc);
        if (j == 0) atomicAdd(&pcnt[run], cacc);
    }
}

// ---------------------------------------------------------------------------
__global__ void pool_fin_kernel(const float* __restrict__ pooled, const float* __restrict__ pcnt,
                                float* __restrict__ emb, float* __restrict__ emb_out)
{
    int gid = blockIdx.x * blockDim.x + threadIdx.x;
    if (gid < NG * H2_) {
        int g = gid >> 7;
        float v = pooled[gid] / fmaxf(pcnt[g], 1.0f);
        emb[gid] = v;
        emb_out[gid] = v;
    }
}

// ---------------------------------------------------------------------------
// classifier MLP, single block, 1024 threads (16 waves for latency hiding)
// ---------------------------------------------------------------------------
__global__ __launch_bounds__(1024) void classifier_kernel(
    const float* __restrict__ emb,
    const float* __restrict__ Wc0, const float* __restrict__ bc0,
    const float* __restrict__ gc0, const float* __restrict__ bec0,
    const float* __restrict__ Wc1, const float* __restrict__ bc1,
    const float* __restrict__ gc1, const float* __restrict__ bec1,
    const float* __restrict__ Wc2, const float* __restrict__ bc2,
    float* __restrict__ logits)
{
    __shared__ float es[NG][H2_];     // 32 KB: emb, later z1
    __shared__ float z0s[NG][256];    // 64 KB
    __shared__ float red_s[1024];     // 4 KB
    __shared__ float red_q[1024];     // 4 KB
    __shared__ float scs[256], shs[256];
    int tid = threadIdx.x;
    for (int i = tid; i < NG * H2_; i += 1024) es[i >> 7][i & 127] = emb[i];
    __syncthreads();

    { // stage A: z0 = relu(bn(emb @ Wc0 + bc0))  [64x128 @ 128x256]
        int j = tid & 255, rg = tid >> 8;          // 4 groups x 16 rows
        float acc[16];
        float b = bc0[j];
        #pragma unroll
        for (int r = 0; r < 16; ++r) acc[r] = b;
        #pragma unroll 4
        for (int k = 0; k < H2_; ++k) {
            float w = Wc0[k * 256 + j];
            #pragma unroll
            for (int r = 0; r < 16; ++r) acc[r] += es[rg * 16 + r][k] * w;
        }
        float cs = 0.f, cq = 0.f;
        #pragma unroll
        for (int r = 0; r < 16; ++r) { cs += acc[r]; cq += acc[r] * acc[r]; }
        red_s[rg * 256 + j] = cs;
        red_q[rg * 256 + j] = cq;
        __syncthreads();
        if (tid < 256) {
            float s = red_s[tid] + red_s[256 + tid] + red_s[512 + tid] + red_s[768 + tid];
            float q = red_q[tid] + red_q[256 + tid] + red_q[512 + tid] + red_q[768 + tid];
            float mu = s * (1.0f / NG);
            float var = q * (1.0f / NG) - mu * mu;
            float sc = gc0[tid] * rsqrtf(var + BN_EPS);
            scs[tid] = sc;
            shs[tid] = bec0[tid] - mu * sc;
        }
        __syncthreads();
        float sc = scs[j], sh = shs[j];
        #pragma unroll
        for (int r = 0; r < 16; ++r)
            z0s[rg * 16 + r][j] = fmaxf(acc[r] * sc + sh, 0.f);
    }
    __syncthreads();

    { // stage B: z1 = relu(bn(z0 @ Wc1 + bc1))  [64x256 @ 256x128] -> es
        int j = tid & 127, rg = tid >> 7;          // 8 groups x 8 rows
        float acc[8];
        float b = bc1[j];
        #pragma unroll
        for (int r = 0; r < 8; ++r) acc[r] = b;
        #pragma unroll 4
        for (int k = 0; k < 256; ++k) {
            float w = Wc1[k * H2_ + j];
            #pragma unroll
            for (int r = 0; r < 8; ++r) acc[r] += z0s[rg * 8 + r][k] * w;
        }
        float cs = 0.f, cq = 0.f;
        #pragma unroll
        for (int r = 0; r < 8; ++r) { cs += acc[r]; cq += acc[r] * acc[r]; }
        red_s[rg * 128 + j] = cs;
        red_q[rg * 128 + j] = cq;
        __syncthreads();
        if (tid < 128) {
            float s = 0.f, q = 0.f;
            #pragma unroll
            for (int g = 0; g < 8; ++g) { s += red_s[g * 128 + tid]; q += red_q[g * 128 + tid]; }
            float mu = s * (1.0f / NG);
            float var = q * (1.0f / NG) - mu * mu;
            float sc = gc1[tid] * rsqrtf(var + BN_EPS);
            scs[tid] = sc;
            shs[tid] = bec1[tid] - mu * sc;
        }
        __syncthreads();
        float sc = scs[j], sh = shs[j];
        #pragma unroll
        for (int r = 0; r < 8; ++r)
            es[rg * 8 + r][j] = fmaxf(acc[r] * sc + sh, 0.f);
    }
    __syncthreads();

    if (tid < NG * NC_) { // stage C: logits = z1 @ Wc2 + bc2
        int r2 = tid >> 1, c = tid & 1;
        float acc = bc2[c];
        #pragma unroll 4
        for (int k = 0; k < H2_; ++k) acc += es[r2][k] * Wc2[k * NC_ + c];
        logits[r2 * NC_ + c] = acc;
    }
}

// ---------------------------------------------------------------------------
extern "C" void kernel_launch(void* const* d_in, const int* in_sizes, int n_in,
                              void* d_out, int out_size, void* d_ws, size_t ws_size,
                              hipStream_t stream)
{
    const float* x    = (const float*)d_in[0];
    const int*   ei   = (const int*)d_in[1];
    const int*   batch= (const int*)d_in[2];
    const float* Wl0  = (const float*)d_in[3];
    const float* bl0  = (const float*)d_in[4];
    const float* Wr0  = (const float*)d_in[5];
    const float* g0   = (const float*)d_in[6];
    const float* be0  = (const float*)d_in[7];
    const float* Wl1  = (const float*)d_in[8];
    const float* bl1  = (const float*)d_in[9];
    const float* Wr1  = (const float*)d_in[10];
    const float* g1   = (const float*)d_in[11];
    const float* be1  = (const float*)d_in[12];
    const float* Wp0  = (const float*)d_in[13];
    const float* bp0  = (const float*)d_in[14];
    const float* Wp1  = (const float*)d_in[15];
    const float* bp1  = (const float*)d_in[16];
    const float* Wc0  = (const float*)d_in[17];
    const float* bc0  = (const float*)d_in[18];
    const float* gc0  = (const float*)d_in[19];
    const float* bec0 = (const float*)d_in[20];
    const float* Wc1  = (const float*)d_in[21];
    const float* bc1  = (const float*)d_in[22];
    const float* gc1  = (const float*)d_in[23];
    const float* bec1 = (const float*)d_in[24];
    const float* Wc2  = (const float*)d_in[25];
    const float* bc2  = (const float*)d_in[26];

    // ---- workspace layout (float units). Total ~36.04M fl = 137.5 MiB
    float* ws = (float*)d_ws;
    float* fs = ws;                              // 32768 small area
    float* ss0       = fs + 768;                 // 512 (scale0, shift0)
    float* ss1       = fs + 1280;                // 256 (scale1, shift1)
    float* pooled    = fs + 1536;                // 8192
    float* pcnt      = fs + 9728;                // 64
    float* emb       = fs + 9792;                // 8192

    unsigned short* wcomb0 = (unsigned short*)(ws + 32768);  // 98304 bf16
    unsigned short* wcomb1 = (unsigned short*)(ws + 81920);  // 98304 bf16

    int* deg    = (int*)(ws + 131072);           // 50000
    int* cursor = deg + 50000;                   // 50000
    int* ell    = cursor + 50000;                // 3,200,000 (PAD_=64 slots/node)

    unsigned short* h0b    = (unsigned short*)(ws + 3431072);   // 12.8M bf16
    unsigned short* xb     = (unsigned short*)(ws + 9831072);   // 6.4M bf16
    unsigned short* meanb0 = (unsigned short*)(ws + 13031072);  // 6.4M bf16
    unsigned short* meanb1 = xb;                 // reuse (12.8M bf16, overlays meanb0)
    float* t0  = ws + 16231072;                  // 12.8M f32
    float* t1  = t0;                             // 6.4M f32 (reuse)
    float* r1  = t0 + 6400000;                   // 6.4M f32 (reuse)
    unsigned short* r0b = (unsigned short*)(ws + 29031072);     // 12.8M bf16
    float* psS0 = ws + 35431072;                 // 782*256 = 200192
    float* psQ0 = psS0 + 200192;                 // 200192
    float* psS1 = psQ0 + 200192;                 // 782*128 = 100096
    float* psQ1 = psS1 + 100096;                 // 100096 (ends 36,031,648)

    float* logits_out = (float*)d_out;
    float* emb_out    = logits_out + NG * NC_;

    hipMemsetAsync(fs, 0, 32768 * sizeof(float), stream);
    hipMemsetAsync(deg, 0, 100000 * sizeof(int), stream);   // deg + cursor

    // ---- prep: ELL adjacency, bf16 x, swizzled weights ----
    degree_kernel<<<(N_EDGES + 255) / 256, 256, 0, stream>>>(ei, deg);
    fill_kernel<<<(N_EDGES + 255) / 256, 256, 0, stream>>>(ei, cursor, ell);
    conv_bf16_kernel<<<(N_NODES * D_IN / 4 + 255) / 256, 256, 0, stream>>>(
        x, xb, N_NODES * D_IN / 4);
    wswz_kernel<D_IN, D_IN, H1_><<<48, 256, 0, stream>>>(Wl0, Wr0, Wp0, wcomb0);
    wswz_kernel<H1_, H1_, H2_><<<48, 256, 0, stream>>>(Wl1, Wr1, Wp1, wcomb1);

    // ---- layer 0 ----
    gather_mean_bf16_kernel<D_IN><<<(N_NODES + 7) / 8, 256, 0, stream>>>(
        xb, deg, ell, meanb0);
    gemm_mfma_kernel<D_IN, D_IN, H1_, true><<<NBLK_G, 256, 0, stream>>>(
        meanb0, xb, wcomb0, bl0, bp0, t0, r0b, psS0, psQ0);
    bn_finalize<H1_><<<H1_, 256, 0, stream>>>(psS0, psQ0, g0, be0, ss0, ss0 + 256);
    ew0_kernel<<<(N_NODES * H1_ / 4 + 255) / 256, 256, 0, stream>>>(
        (const float4*)t0, (const ushort4*)r0b, ss0, ss0 + 256, (ushort4*)h0b);

    // ---- layer 1 ----
    gather_mean_bf16_kernel<H1_><<<(N_NODES + 3) / 4, 256, 0, stream>>>(
        h0b, deg, ell, meanb1);
    gemm_mfma_kernel<H1_, H1_, H2_, false><<<NBLK_G, 256, 0, stream>>>(
        meanb1, h0b, wcomb1, bl1, bp1, t1, r1, psS1, psQ1);
    bn_finalize<H2_><<<H2_, 256, 0, stream>>>(psS1, psQ1, g1, be1, ss1, ss1 + 128);
    ew1_pool_kernel<<<(N_NODES + 63) / 64, H2_, 0, stream>>>(
        t1, r1, ss1, ss1 + 128, batch, pooled, pcnt);

    // ---- pooling + classifier ----
    pool_fin_kernel<<<32, 256, 0, stream>>>(pooled, pcnt, emb, emb_out);
    classifier_kernel<<<1, 1024, 0, stream>>>(
        emb, Wc0, bc0, gc0, bec0, Wc1, bc1, gc1, bec1, Wc2, bc2, logits_out);
}